// Round 11
// baseline (281.593 us; speedup 1.0000x reference)
//
#include <hip/hip_runtime.h>
#include <math.h>

#define D_MODEL 1024
#define D_STATE 16
#define D_CONVK 4
#define D_INNER 2048
#define DT_RANK 64
#define BB 2
#define LL 2048
#define NROWS (BB*LL)   // 4096
#define NC 64           // scan chunks
#define CH (LL/NC)      // 32 steps per chunk
#define XZLD 4096       // fused xz bf16 row stride
#define LOG2E 1.44269504088896340736f
#define LN2   0.69314718055994530942f

typedef __attribute__((ext_vector_type(8))) short bf16x8;
typedef __attribute__((ext_vector_type(8))) unsigned short u16x8;
typedef __attribute__((ext_vector_type(4))) float f32x4;

typedef __attribute__((address_space(3))) unsigned char lds_ucp;
typedef const __attribute__((address_space(1))) unsigned char glb_ucp;
#define GLD16(gp, lp) __builtin_amdgcn_global_load_lds((glb_ucp*)(gp), (lds_ucp*)(lp), 16, 0, 0)

__device__ inline unsigned short f2bf(float f) {
    union { float f; unsigned u; } c; c.f = f;
    unsigned r = c.u + 0x7fff + ((c.u >> 16) & 1);   // round-to-nearest-even
    return (unsigned short)(r >> 16);
}
__device__ inline float bf2f(unsigned short s) {
    union { unsigned u; float f; } c; c.u = ((unsigned)s) << 16;
    return c.f;
}
__device__ inline float fexp2(float x) { return __builtin_amdgcn_exp2f(x); }
__device__ inline float frcp(float x)  { return __builtin_amdgcn_rcpf(x); }
__device__ inline float fsilu(float x) { return x * frcp(1.0f + fexp2(-x * LOG2E)); }

// ---- merged prologue: LN (bx<4096) + all 4 weight transposes (bx>=4096) ----
__global__ __launch_bounds__(256)
void prologue_kernel(const float* __restrict__ x, const float* __restrict__ lw,
                     const float* __restrict__ lb, unsigned short* __restrict__ xnb,
                     const float* __restrict__ Win, const float* __restrict__ Wout,
                     const float* __restrict__ Wx, const float* __restrict__ Wdt,
                     unsigned short* __restrict__ wtin, unsigned short* __restrict__ wtout,
                     unsigned short* __restrict__ Wxt, unsigned short* __restrict__ Wdtt) {
    if (blockIdx.x < NROWS) {
        int row = blockIdx.x;
        const float* xr = x + (size_t)row * D_MODEL;
        float4 v = ((const float4*)xr)[threadIdx.x];
        float s  = v.x + v.y + v.z + v.w;
        float ss = v.x*v.x + v.y*v.y + v.z*v.z + v.w*v.w;
        for (int off = 32; off > 0; off >>= 1) {
            s  += __shfl_down(s, off);
            ss += __shfl_down(ss, off);
        }
        __shared__ float red[8];
        int lane = threadIdx.x & 63, wv = threadIdx.x >> 6;
        if (lane == 0) { red[wv] = s; red[wv + 4] = ss; }
        __syncthreads();
        if (threadIdx.x == 0) {
            float ts  = red[0] + red[1] + red[2] + red[3];
            float tss = red[4] + red[5] + red[6] + red[7];
            float mu  = ts / D_MODEL;
            float var = tss / D_MODEL - mu * mu;
            red[0] = mu; red[1] = rsqrtf(var + 1e-5f);
        }
        __syncthreads();
        float mu = red[0], rs = red[1];
        float4 w4 = ((const float4*)lw)[threadIdx.x];
        float4 b4 = ((const float4*)lb)[threadIdx.x];
        ushort4 o;
        o.x = f2bf((v.x - mu) * rs * w4.x + b4.x);
        o.y = f2bf((v.y - mu) * rs * w4.y + b4.y);
        o.z = f2bf((v.z - mu) * rs * w4.z + b4.z);
        o.w = f2bf((v.w - mu) * rs * w4.w + b4.w);
        ((ushort4*)(xnb + (size_t)row * D_MODEL))[threadIdx.x] = o;
        return;
    }
    int tb = blockIdx.x - NROWS;
    int bx = tb % 228, by = tb / 228;
    __shared__ float t[32][33];
    const float* W; unsigned short* Wt; int K, Nsrc, xb;
    if (bx < 128)      { W = Win;  Wt = wtin;  K = 1024; Nsrc = 4096; xb = bx; }
    else if (bx < 160) { W = Wout; Wt = wtout; K = 2048; Nsrc = 1024; xb = bx - 128; }
    else if (bx < 164) { W = Wx;   Wt = Wxt;   K = 2048; Nsrc = 96;   xb = bx - 160; }
    else               { W = Wdt;  Wt = Wdtt;  K = 64;   Nsrc = 2048; xb = bx - 164; }
    int k0 = by * 32, n0 = xb * 32;
    if (k0 >= K) return;
    int tx = threadIdx.x & 31, ty = threadIdx.x >> 5;
#pragma unroll
    for (int i = 0; i < 32; i += 8)
        t[ty + i][tx] = (n0 + tx < Nsrc)
            ? W[(size_t)(k0 + ty + i) * Nsrc + n0 + tx] : 0.0f;
    __syncthreads();
#pragma unroll
    for (int i = 0; i < 32; i += 8)
        Wt[(size_t)(n0 + ty + i) * K + k0 + tx] = f2bf(t[tx][ty + i]);
}

// ---- pipelined bf16 MFMA GEMM: 256x128 tile, BK=32, ring-2, 1 barrier/tile,
// 48 KB LDS. The register-FEASIBLE high-occupancy config: per-wave 64x64
// output -> acc[4][4] = 64 VGPR (r0's same-shape kernel reported VGPR=64),
// so with (512,2) cap=256 there is NO spill risk and actual regs <=128 give
// 2-3 blocks/CU automatically (occupancy from actuals, not from the bound --
// r7 lesson). Schedule = r7-verified ring-2 1-barrier; swizzle = r2-verified
// 0-conflict involution; epilogue = r0-verified 256x128 pair-packed mapping.
__global__ __launch_bounds__(512, 2)
void mfma_gemm_pipe(const unsigned short* __restrict__ A,
                    const unsigned short* __restrict__ Wt,
                    int ldc, int K, unsigned short* __restrict__ out2) {
    __shared__ short As[2][256 * 32];   // 16 KB/buf
    __shared__ short Bs[2][128 * 32];   // 8 KB/buf  -> 48 KB total
    int tid = threadIdx.x;
    int lane = tid & 63, w = tid >> 6;
    int wm = w & 3, wn = w >> 2;        // 4 M-strips(64) x 2 N-strips(64)
    // bijective XCD swizzle (grid 32x16 = 512, 512 % 8 == 0)
    int bid = blockIdx.y * gridDim.x + blockIdx.x;
    int cpx = (gridDim.x * gridDim.y) >> 3;
    int swz = (bid & 7) * cpx + (bid >> 3);
    int bx = swz % gridDim.x, by = swz / gridDim.x;
    int row0 = by * 256, col0 = bx * 128;
    const unsigned short* gA0 = A  + (size_t)row0 * K;
    const unsigned short* gB0 = Wt + (size_t)col0 * K;
    // staging: chunk (1KB) = 16 rows x 32 elems; lane -> row lane>>2, slot
    // lane&3; pre-swizzled global col: slot ^ ((row>>1)&3). Chunks 16-row
    // aligned -> (absrow>>1)&3 == (rowin>>1)&3, involution consistent.
    int rowin = lane >> 2;
    int scol  = ((lane & 3) ^ ((lane >> 3) & 3)) << 3;
    int quad = lane >> 4, r16 = lane & 15;
    int swr  = (r16 >> 1) & 3;              // read-side swizzle (row>>1)&3
    int cslot = ((quad ^ swr) << 3);
    f32x4 acc[4][4] = {};
    int nt = K >> 5;                        // 32 for K=1024

    // A: 16 chunks (2/wave), B: 8 chunks (1/wave) -> 3 GLD/wave/tile
#define STAGE(tt) do { int _b = (tt) & 1; int _k0 = (tt) << 5;                 \
    _Pragma("unroll")                                                          \
    for (int _l = 0; _l < 2; ++_l) {                                           \
        int _c = _l * 8 + w;                                                   \
        GLD16(gA0 + (size_t)(_c * 16 + rowin) * K + _k0 + scol,                \
              (char*)&As[_b][0] + _c * 1024);                                  \
    }                                                                          \
    GLD16(gB0 + (size_t)(w * 16 + rowin) * K + _k0 + scol,                     \
          (char*)&Bs[_b][0] + w * 1024);  } while (0)

    STAGE(0);                               // 3 loads in flight

#pragma unroll 4
    for (int t = 0; t < nt; ++t) {
        // outstanding at tile top = own stage(t) loads (issued a full tile
        // earlier except t=0). Ring-2 hazards per r7-verified construction:
        // stage(t+1) after barrier(t) targets the buffer whose t-1 reads
        // globally completed before any wave passed barrier(t).
        asm volatile("s_waitcnt vmcnt(0)" ::: "memory");
        __builtin_amdgcn_s_barrier();
        const short* Ab = &As[t & 1][0];
        const short* Bb = &Bs[t & 1][0];
        bf16x8 bfr[4], af[4];
#pragma unroll
        for (int i = 0; i < 4; ++i)
            bfr[i] = *(const bf16x8*)&Bb[(wn * 64 + i * 16 + r16) * 32 + cslot];
#pragma unroll
        for (int i = 0; i < 4; ++i)
            af[i] = *(const bf16x8*)&Ab[(wm * 64 + i * 16 + r16) * 32 + cslot];
        if (t + 1 < nt) STAGE(t + 1);
        __builtin_amdgcn_s_setprio(1);
#pragma unroll
        for (int mi = 0; mi < 4; ++mi)
#pragma unroll
            for (int ni = 0; ni < 4; ++ni)
                acc[mi][ni] = __builtin_amdgcn_mfma_f32_16x16x32_bf16(
                    af[mi], bfr[ni], acc[mi][ni], 0, 0, 0);
        __builtin_amdgcn_s_setprio(0);
    }
#undef STAGE
    // epilogue: pair-packed bf16 stores (r0-verified 256x128 mapping)
    int odd = lane & 1;
#pragma unroll
    for (int mi = 0; mi < 4; ++mi)
#pragma unroll
        for (int ni = 0; ni < 4; ++ni) {
            int colE = col0 + wn * 64 + ni * 16 + r16;
#pragma unroll
            for (int rp = 0; rp < 2; ++rp) {
                int rowE = row0 + wm * 64 + mi * 16 + quad * 4 + rp * 2;
                int row  = rowE + odd;
                int colp = colE - odd;
                unsigned hh = (unsigned)f2bf(acc[mi][ni][rp*2]) |
                              ((unsigned)f2bf(acc[mi][ni][rp*2+1]) << 16);
                unsigned ph = __shfl_xor((int)hh, 1);
                unsigned u_even = (hh & 0xffffu) | (ph << 16);
                unsigned u_odd  = (ph >> 16) | (hh & 0xffff0000u);
                unsigned u = odd ? u_odd : u_even;
                *(unsigned*)&out2[(size_t)row * ldc + colp] = u;
            }
        }
}

// ---- pipelined out_proj: 128x128, BK=64, 4-deep ring, 1 barrier/tile,
// fused epilogue out = rs*acc + residual. EXACT round-5 verified state.
__global__ __launch_bounds__(512, 2)
void mfma_out_pipe(const unsigned short* __restrict__ A,
                   const unsigned short* __restrict__ Wt,
                   const float* __restrict__ x, const float* __restrict__ rscale,
                   float* __restrict__ out) {
    __shared__ short As[4][128 * 64];   // 64 KB
    __shared__ short Bs[4][128 * 64];   // 64 KB
    const int K = D_INNER;              // 2048
    int tid = threadIdx.x;
    int lane = tid & 63, w = tid >> 6;
    int wm = w & 1, wn = w >> 1;        // 2 M-strips(64) x 4 N-strips(32)
    // bijective XCD swizzle (grid 256 % 8 == 0)
    int bid = blockIdx.y * gridDim.x + blockIdx.x;
    int cpx = (gridDim.x * gridDim.y) >> 3;
    int swz = (bid & 7) * cpx + (bid >> 3);
    int bx = swz % gridDim.x, by = swz / gridDim.x;
    int row0 = by * 128, col0 = bx * 128;
    const unsigned short* gA0 = A  + (size_t)row0 * K;
    const unsigned short* gB0 = Wt + (size_t)col0 * K;
    int row8 = lane >> 3;
    int scol = ((lane & 7) ^ row8) << 3;
    int quad = lane >> 4, r16 = lane & 15;
    int sw7  = r16 & 7;                 // read-side swizzle row&7
    f32x4 acc[4][2] = {};
    const int nt = K >> 6;              // 32

#define OSTG(gp, buf, tt) do { int _b = (tt) & 3; int _k0 = (tt) << 6;         \
    _Pragma("unroll")                                                          \
    for (int _l = 0; _l < 2; ++_l) {                                           \
        int _c = _l * 8 + w;                                                   \
        GLD16(gp + (size_t)(_c * 8 + row8) * K + _k0 + scol,                   \
              (char*)&buf[_b][0] + _c * 1024);                                 \
    } } while (0)

    OSTG(gA0, As, 0); OSTG(gB0, Bs, 0); OSTG(gA0, As, 1); OSTG(gB0, Bs, 1);

#pragma unroll 4
    for (int t = 0; t < nt; ++t) {
        if (t < nt - 1) asm volatile("s_waitcnt vmcnt(4)" ::: "memory");
        else            asm volatile("s_waitcnt vmcnt(0)" ::: "memory");
        __builtin_amdgcn_s_barrier();
        const short* Ab = &As[t & 3][0];
        const short* Bb = &Bs[t & 3][0];
        int cs0 = ((quad ^ sw7) << 3);
        int cs1 = (((4 + quad) ^ sw7) << 3);
        bf16x8 af0[4], af1[4], bf0[2], bf1[2];
#pragma unroll
        for (int i = 0; i < 2; ++i) {
            bf0[i] = *(const bf16x8*)&Bb[(wn * 32 + i * 16 + r16) * 64 + cs0];
            bf1[i] = *(const bf16x8*)&Bb[(wn * 32 + i * 16 + r16) * 64 + cs1];
        }
#pragma unroll
        for (int i = 0; i < 4; ++i) {
            af0[i] = *(const bf16x8*)&Ab[(wm * 64 + i * 16 + r16) * 64 + cs0];
            af1[i] = *(const bf16x8*)&Ab[(wm * 64 + i * 16 + r16) * 64 + cs1];
        }
        if (t + 2 < nt) { OSTG(gA0, As, t + 2); OSTG(gB0, Bs, t + 2); }
        __builtin_amdgcn_s_setprio(1);
#pragma unroll
        for (int mi = 0; mi < 4; ++mi)
#pragma unroll
            for (int ni = 0; ni < 2; ++ni)
                acc[mi][ni] = __builtin_amdgcn_mfma_f32_16x16x32_bf16(
                    af0[mi], bf0[ni], acc[mi][ni], 0, 0, 0);
#pragma unroll
        for (int mi = 0; mi < 4; ++mi)
#pragma unroll
            for (int ni = 0; ni < 2; ++ni)
                acc[mi][ni] = __builtin_amdgcn_mfma_f32_16x16x32_bf16(
                    af1[mi], bf1[ni], acc[mi][ni], 0, 0, 0);
        __builtin_amdgcn_s_setprio(0);
    }
#undef OSTG
    // fused epilogue: out = rs*acc + residual (pair-packed fp32, proven)
    float rs = rscale[0];
    int odd = lane & 1;
#pragma unroll
    for (int mi = 0; mi < 4; ++mi)
#pragma unroll
        for (int ni = 0; ni < 2; ++ni) {
            int colE = col0 + wn * 32 + ni * 16 + r16;
#pragma unroll
            for (int rp = 0; rp < 2; ++rp) {
                int rowE = row0 + wm * 64 + mi * 16 + quad * 4 + rp * 2;
                int row  = rowE + odd;
                int colp = colE - odd;
                float a0 = acc[mi][ni][rp*2], a1 = acc[mi][ni][rp*2+1];
                float b0 = __shfl_xor(a0, 1), b1 = __shfl_xor(a1, 1);
                float2 f2;
                f2.x = odd ? b1 : a0;
                f2.y = odd ? a1 : b0;
                float2 xr = *(const float2*)&x[(size_t)row * D_MODEL + colp];
                float2 o2;
                o2.x = rs * f2.x + xr.x;
                o2.y = rs * f2.y + xr.y;
                *(float2*)&out[(size_t)row * D_MODEL + colp] = o2;
            }
        }
}

// ---------------- bf16 MFMA GEMM: 128x128, 256 threads, BK=64 --------------
// mode 0: fp32 pair-packed if col<Ncols | mode 4: softplus(acc+aux[col]) bf16
__global__ __launch_bounds__(256)
void mfma_gemm(const unsigned short* __restrict__ A,
               const unsigned short* __restrict__ Wt,
               float* __restrict__ C, int ldc, int K, int kchunk,
               size_t zstride, int mode,
               const float* __restrict__ aux,
               int Ncols, unsigned short* __restrict__ out2) {
    __shared__ short As[128 * 64];
    __shared__ short Bs[128 * 64];
    int tid = threadIdx.x;
    int lane = tid & 63, w = tid >> 6;
    int wm = w & 1, wn = w >> 1;
    int row0 = blockIdx.y * 128, col0 = blockIdx.x * 128;
    int kb = blockIdx.z * kchunk, ke = kb + kchunk;
    C += (size_t)blockIdx.z * zstride;
    f32x4 acc[4][4] = {};
    const unsigned short* gA0 = A  + (size_t)row0 * K;
    const unsigned short* gB0 = Wt + (size_t)col0 * K;
    int r_in = lane >> 3;
    int e16  = (lane & 7) * 8;
    int quad = lane >> 4, r16 = lane & 15;
    for (int k0 = kb; k0 < ke; k0 += 64) {
        __syncthreads();
#pragma unroll
        for (int t = 0; t < 4; ++t) {
            int p = w * 4 + t;
            int row = p * 8 + r_in;
            GLD16(gA0 + (size_t)row * K + k0 + e16, (char*)As + p * 1024);
            GLD16(gB0 + (size_t)row * K + k0 + e16, (char*)Bs + p * 1024);
        }
        __syncthreads();
#pragma unroll
        for (int ks = 0; ks < 2; ++ks) {
            bf16x8 af[4], bfr[4];
#pragma unroll
            for (int i = 0; i < 4; ++i) {
                af[i]  = *(const bf16x8*)&As[(wm * 64 + i * 16 + r16) * 64 + ks * 32 + quad * 8];
                bfr[i] = *(const bf16x8*)&Bs[(wn * 64 + i * 16 + r16) * 64 + ks * 32 + quad * 8];
            }
#pragma unroll
            for (int mi = 0; mi < 4; ++mi)
#pragma unroll
                for (int ni = 0; ni < 4; ++ni)
                    acc[mi][ni] = __builtin_amdgcn_mfma_f32_16x16x32_bf16(
                        af[mi], bfr[ni], acc[mi][ni], 0, 0, 0);
        }
    }
    int odd = lane & 1;
#pragma unroll
    for (int mi = 0; mi < 4; ++mi)
#pragma unroll
        for (int ni = 0; ni < 4; ++ni) {
            int colE = col0 + wn * 64 + ni * 16 + r16;
            float v[4];
#pragma unroll
            for (int r = 0; r < 4; ++r) v[r] = acc[mi][ni][r];
            if (mode == 4) {
                float bv = aux[colE];
#pragma unroll
                for (int r = 0; r < 4; ++r) {
                    float tv = v[r] + bv;
                    v[r] = (tv > 20.0f) ? tv
                         : LN2 * __builtin_amdgcn_logf(1.0f + fexp2(tv * LOG2E));
                }
            }
#pragma unroll
            for (int rp = 0; rp < 2; ++rp) {
                int rowE = row0 + wm * 64 + mi * 16 + quad * 4 + rp * 2;
                int row  = rowE + odd;
                int colp = colE - odd;
                if (mode >= 3) {
                    unsigned hh = (unsigned)f2bf(v[rp*2]) | ((unsigned)f2bf(v[rp*2+1]) << 16);
                    unsigned ph = __shfl_xor((int)hh, 1);
                    unsigned u_even = (hh & 0xffffu) | (ph << 16);
                    unsigned u_odd  = (ph >> 16) | (hh & 0xffff0000u);
                    unsigned u = odd ? u_odd : u_even;
                    *(unsigned*)&out2[(size_t)row * ldc + colp] = u;
                } else {
                    float a0 = v[rp*2], a1 = v[rp*2+1];
                    float b0 = __shfl_xor(a0, 1), b1 = __shfl_xor(a1, 1);
                    float2 f2;
                    f2.x = odd ? b1 : a0;
                    f2.y = odd ? a1 : b0;
                    if (colp < Ncols)
                        *(float2*)&C[(size_t)row * ldc + colp] = f2;
                }
            }
        }
}

// ---- reduce 8 split-K partials of x_dbl; emit dt-rank bf16 + B|C fp32 ----
__global__ __launch_bounds__(256)
void xdbl_reduce(const float* __restrict__ P,
                 unsigned short* __restrict__ xdtr, float* __restrict__ xbc) {
    const int S1 = NROWS * 96;
    int t = blockIdx.x * 256 + threadIdx.x;
    float s = 0.0f;
#pragma unroll
    for (int k = 0; k < 8; ++k) s += P[t + k * S1];
    int row = t / 96, col = t - row * 96;
    if (col < DT_RANK) xdtr[(size_t)row * DT_RANK + col] = f2bf(s);
    else xbc[(size_t)row * 32 + col - DT_RANK] = s;
}

// ---- Causal depthwise conv (K=4) + bias + silu, bf16 in/out, vectorized ----
__global__ __launch_bounds__(256)
void conv_kernel(const unsigned short* __restrict__ xzb, const float* __restrict__ cw,
                 const float* __restrict__ cb, unsigned short* __restrict__ xs,
                 float* __restrict__ conv_state_out) {
    int loct = blockIdx.x & 255;
    int b    = blockIdx.x >> 8;
    int d0   = threadIdx.x * 8;
    float wgt[8][4];
#pragma unroll
    for (int j = 0; j < 8; ++j) {
        float4 w4 = *(const float4*)(cw + (size_t)(d0 + j) * 4);
        wgt[j][0] = w4.x; wgt[j][1] = w4.y; wgt[j][2] = w4.z; wgt[j][3] = w4.w;
    }
    float bias[8];
    *(float4*)&bias[0] = *(const float4*)(cb + d0);
    *(float4*)&bias[4] = *(const float4*)(cb + d0 + 4);
    float xr[11][8];
#pragma unroll
    for (int r = 0; r < 11; ++r) {
        int l = loct * 8 - 3 + r;
        if (l >= 0) {
            u16x8 v = *(const u16x8*)&xzb[((size_t)b * LL + l) * XZLD + d0];
#pragma unroll
            for (int j = 0; j < 8; ++j) xr[r][j] = bf2f(v[j]);
        } else {
#pragma unroll
            for (int j = 0; j < 8; ++j) xr[r][j] = 0.0f;
        }
    }
#pragma unroll
    for (int i = 0; i < 8; ++i) {
        unsigned short o[8];
#pragma unroll
        for (int j = 0; j < 8; ++j) {
            float a = bias[j];
#pragma unroll
            for (int k = 0; k < 4; ++k) a = fmaf(xr[i + k][j], wgt[j][k], a);
            o[j] = f2bf(fsilu(a));
        }
        *(u16x8*)&xs[((size_t)b * LL + loct * 8 + i) * D_INNER + d0] = *(u16x8*)o;
    }
    if (loct == 255) {
#pragma unroll
        for (int i = 8; i < 11; ++i)
#pragma unroll
            for (int j = 0; j < 8; ++j)
                conv_state_out[((size_t)b * D_INNER + d0 + j) * 3 + (i - 8)] = xr[i][j];
    }
}

// ---------------- Selective scan: thread-per-d, 16 n-states in regs --------
// Pass 1: chunk-local scan S[16] + Tsum (chunk dt sum). E never materialized.
__global__ __launch_bounds__(256)
void scan_part1(const unsigned short* __restrict__ dt, const float* __restrict__ xbc,
                const unsigned short* __restrict__ xs,
                const float* __restrict__ A_log,
                float* __restrict__ Sbuf, float* __restrict__ Tbuf) {
    __shared__ float Bs[CH][32];
    int d = blockIdx.x * 256 + threadIdx.x;
    int c = blockIdx.y, b = blockIdx.z;
    size_t rowbase = (size_t)b * LL + (size_t)c * CH;
    for (int e = threadIdx.x; e < CH * 32; e += 256) {
        int i = e >> 5, j = e & 31;
        Bs[i][j] = xbc[(rowbase + i) * 32 + j];
    }
    float al2[16];
    {
        const float4* ap = (const float4*)(A_log + (size_t)d * D_STATE);
#pragma unroll
        for (int q = 0; q < 4; ++q) {
            float4 a4 = ap[q];
            al2[q*4+0] = -fexp2(a4.x * LOG2E) * LOG2E;
            al2[q*4+1] = -fexp2(a4.y * LOG2E) * LOG2E;
            al2[q*4+2] = -fexp2(a4.z * LOG2E) * LOG2E;
            al2[q*4+3] = -fexp2(a4.w * LOG2E) * LOG2E;
        }
    }
    __syncthreads();
    float S[16];
#pragma unroll
    for (int n = 0; n < 16; ++n) S[n] = 0.0f;
    float Tsum = 0.0f;
    float dtv = bf2f(dt[rowbase * D_INNER + d]);
    float xv  = bf2f(xs[rowbase * D_INNER + d]);
    for (int i = 0; i < CH; ++i) {
        float dtn = 0.0f, xn2 = 0.0f;
        if (i + 1 < CH) {
            size_t r2 = (rowbase + i + 1) * D_INNER + d;
            dtn = bf2f(dt[r2]); xn2 = bf2f(xs[r2]);
        }
        Tsum += dtv;
        float dtx = dtv * xv;
#pragma unroll
        for (int q = 0; q < 4; ++q) {
            float4 Bv = *(const float4*)&Bs[i][q * 4];
            S[q*4+0] = fmaf(fexp2(al2[q*4+0] * dtv), S[q*4+0], dtx * Bv.x);
            S[q*4+1] = fmaf(fexp2(al2[q*4+1] * dtv), S[q*4+1], dtx * Bv.y);
            S[q*4+2] = fmaf(fexp2(al2[q*4+2] * dtv), S[q*4+2], dtx * Bv.z);
            S[q*4+3] = fmaf(fexp2(al2[q*4+3] * dtv), S[q*4+3], dtx * Bv.w);
        }
        dtv = dtn; xv = xn2;
    }
    size_t o = (((size_t)b * NC + c) * D_INNER + d) * D_STATE;
#pragma unroll
    for (int q = 0; q < 4; ++q) {
        float4 Sv;
        Sv.x = S[q*4+0]; Sv.y = S[q*4+1]; Sv.z = S[q*4+2]; Sv.w = S[q*4+3];
        *(float4*)(Sbuf + o + q * 4) = Sv;
    }
    Tbuf[((size_t)b * NC + c) * D_INNER + d] = Tsum;
}

// Pass 2: fold chunks; E recomputed from Tsum. Hin aliases Sbuf (load-then-store).
__global__ __launch_bounds__(256)
void scan_part2(const float* __restrict__ S, const float* __restrict__ Tbuf,
                const float* __restrict__ A_log, float* __restrict__ Hin) {
    int t = blockIdx.x * 256 + threadIdx.x;
    int b = t >> 15;
    int rem = t & 32767;          // d*16+n
    int d = rem >> 4;
    float al2 = -fexp2(A_log[rem] * LOG2E) * LOG2E;
    size_t sbase = (size_t)b * NC * (D_INNER * D_STATE) + rem;
    size_t tbase = (size_t)b * NC * D_INNER + d;
    float h = 0.0f;
    for (int c = 0; c < NC; ++c) {
        size_t sq = sbase + (size_t)c * (D_INNER * D_STATE);
        float s = S[sq];
        float T = Tbuf[tbase + (size_t)c * D_INNER];
        Hin[sq] = h;
        h = fmaf(fexp2(al2 * T), h, s);
    }
}

// Pass 3: local scan with h_in; emits y (bf16) and final ssm state.
__global__ __launch_bounds__(256)
void scan_part3(const unsigned short* __restrict__ dt, const float* __restrict__ xbc,
                const unsigned short* __restrict__ xs,
                const unsigned short* __restrict__ xzb,  // z at col 2048+, stride XZLD
                const float* __restrict__ A_log, const float* __restrict__ Dp,
                const float* __restrict__ Hin,
                unsigned short* __restrict__ y, float* __restrict__ ssm_out) {
    __shared__ float Bs[CH][32];
    int d = blockIdx.x * 256 + threadIdx.x;
    int c = blockIdx.y, b = blockIdx.z;
    size_t rowbase = (size_t)b * LL + (size_t)c * CH;
    for (int e = threadIdx.x; e < CH * 32; e += 256) {
        int i = e >> 5, j = e & 31;
        Bs[i][j] = xbc[(rowbase + i) * 32 + j];
    }
    float al2[16];
    {
        const float4* ap = (const float4*)(A_log + (size_t)d * D_STATE);
#pragma unroll
        for (int q = 0; q < 4; ++q) {
            float4 a4 = ap[q];
            al2[q*4+0] = -fexp2(a4.x * LOG2E) * LOG2E;
            al2[q*4+1] = -fexp2(a4.y * LOG2E) * LOG2E;
            al2[q*4+2] = -fexp2(a4.z * LOG2E) * LOG2E;
            al2[q*4+3] = -fexp2(a4.w * LOG2E) * LOG2E;
        }
    }
    float Dv = Dp[d];
    float h[16];
    {
        const float4* hp = (const float4*)(Hin + (((size_t)b * NC + c) * D_INNER + d) * D_STATE);
#pragma unroll
        for (int q = 0; q < 4; ++q) {
            float4 h4 = hp[q];
            h[q*4+0] = h4.x; h[q*4+1] = h4.y; h[q*4+2] = h4.z; h[q*4+3] = h4.w;
        }
    }
    __syncthreads();
    size_t r0 = rowbase * D_INNER + d;
    float dtv = bf2f(dt[r0]);
    float xv  = bf2f(xs[r0]);
    float zv  = bf2f(xzb[rowbase * XZLD + D_INNER + d]);
    for (int i = 0; i < CH; ++i) {
        float dtn = 0.0f, xn2 = 0.0f, zn2 = 0.0f;
        if (i + 1 < CH) {
            size_t r2 = (rowbase + i + 1) * D_INNER + d;
            dtn = bf2f(dt[r2]); xn2 = bf2f(xs[r2]);
            zn2 = bf2f(xzb[(rowbase + i + 1) * XZLD + D_INNER + d]);
        }
        float dtx = dtv * xv;
        float yv = 0.0f;
#pragma unroll
        for (int q = 0; q < 4; ++q) {
            float4 Bv = *(const float4*)&Bs[i][q * 4];
            float4 Cv = *(const float4*)&Bs[i][16 + q * 4];
            h[q*4+0] = fmaf(fexp2(al2[q*4+0] * dtv), h[q*4+0], dtx * Bv.x);
            h[q*4+1] = fmaf(fexp2(al2[q*4+1] * dtv), h[q*4+1], dtx * Bv.y);
            h[q*4+2] = fmaf(fexp2(al2[q*4+2] * dtv), h[q*4+2], dtx * Bv.z);
            h[q*4+3] = fmaf(fexp2(al2[q*4+3] * dtv), h[q*4+3], dtx * Bv.w);
            yv = fmaf(h[q*4+0], Cv.x, yv);
            yv = fmaf(h[q*4+1], Cv.y, yv);
            yv = fmaf(h[q*4+2], Cv.z, yv);
            yv = fmaf(h[q*4+3], Cv.w, yv);
        }
        yv = (yv + xv * Dv) * fsilu(zv);
        y[(rowbase + i) * D_INNER + d] = f2bf(yv);
        dtv = dtn; xv = xn2; zv = zn2;
    }
    if (c == NC - 1) {
        float* sp = ssm_out + ((size_t)b * D_INNER + d) * D_STATE;
#pragma unroll
        for (int q = 0; q < 4; ++q) {
            float4 h4;
            h4.x = h[q*4+0]; h4.y = h[q*4+1]; h4.z = h[q*4+2]; h4.w = h[q*4+3];
            *(float4*)(sp + q * 4) = h4;
        }
    }
}

// ---------------- launch ----------------
extern "C" void kernel_launch(void* const* d_in, const int* in_sizes, int n_in,
                              void* d_out, int out_size, void* d_ws, size_t ws_size,
                              hipStream_t stream) {
    (void)in_sizes; (void)n_in; (void)out_size; (void)ws_size;
    const float* x      = (const float*)d_in[0];
    const float* ln_w   = (const float*)d_in[1];
    const float* ln_b   = (const float*)d_in[2];
    const float* Win    = (const float*)d_in[3];   // [1024, 4096]
    const float* convw  = (const float*)d_in[4];   // [2048, 4]
    const float* convb  = (const float*)d_in[5];
    const float* Wx     = (const float*)d_in[6];   // [2048, 96]
    const float* Wdt    = (const float*)d_in[7];   // [64, 2048]
    const float* bdt    = (const float*)d_in[8];
    const float* A_log  = (const float*)d_in[9];   // [2048, 16]
    const float* Dp     = (const float*)d_in[10];
    const float* Wout   = (const float*)d_in[11];  // [2048, 1024]
    const float* rscale = (const float*)d_in[12];  // [1]

    float* out      = (float*)d_out;
    float* ssm_out  = out + (size_t)NROWS * D_MODEL;
    float* conv_out = ssm_out + (size_t)BB * D_INNER * D_STATE;

    // ---- workspace layout ----
    float* ws = (float*)d_ws;
    unsigned short* xzb = (unsigned short*)ws;                     // 33.55 MB bf16
    unsigned short* xsb = xzb + (size_t)NROWS * XZLD;              // 16.78 MB bf16
    unsigned short* dtbb = xsb + (size_t)NROWS * D_INNER;          // 16.78 MB bf16
    float* xbc  = (float*)(dtbb + (size_t)NROWS * D_INNER);        // 0.52 MB
    unsigned short* xdtr = (unsigned short*)(xbc + (size_t)NROWS * 32);  // 0.52 MB
    unsigned short* xnb  = xdtr + (size_t)NROWS * DT_RANK;         // 8.39 MB
    unsigned short* wtin = xnb + (size_t)NROWS * D_MODEL;          // 8.39 MB
    unsigned short* wtout = wtin + (size_t)(2 * D_INNER) * D_MODEL; // 4.19 MB
    unsigned short* Wxt  = wtout + (size_t)D_MODEL * D_INNER;      // 0.52 MB
    unsigned short* Wdtt = Wxt + (size_t)128 * D_INNER;            // 0.26 MB
    float* Tbuf = (float*)(Wdtt + (size_t)D_INNER * DT_RANK);      // 1.05 MB (NC=64)
    float* Sbuf = Tbuf + (size_t)BB * NC * D_INNER;                // 16.78 MB (NC=64)
    // aliases (disjoint lifetimes within Sbuf region):
    float* Pxdbl = Sbuf;                         // 12.58 MB, dead before scan1
    float* Hin   = Sbuf;                         // pass2 out (load-before-store)
    unsigned short* ybuf = xnb;                  // y bf16 spans xnb+wtin (dead)

    // 1. LN + all weight transposes (one launch)
    prologue_kernel<<<NROWS + 228 * 64, 256, 0, stream>>>(
        x, ln_w, ln_b, xnb, Win, Wout, Wx, Wdt, wtin, wtout, Wxt, Wdtt);

    // 2. in_proj: pipelined 256x128, BK=32, ring-2, 48KB LDS (2-3 blocks/CU)
    mfma_gemm_pipe<<<dim3(2 * D_INNER / 128, NROWS / 256), 512, 0, stream>>>(
        xnb, wtin, XZLD, D_MODEL, xzb);

    // 3. conv + silu -> bf16 x_s (+ conv_state)
    conv_kernel<<<BB * (LL / 8), 256, 0, stream>>>(
        xzb, convw, convb, xsb, conv_out);

    // 4. x_dbl split-K x8 -> partials (MFMA), then reduce
    mfma_gemm<<<dim3(1, NROWS / 128, 8), 256, 0, stream>>>(
        xsb, Wxt, Pxdbl, 96, D_INNER, D_INNER / 8, (size_t)NROWS * 96, 0,
        nullptr, 96, nullptr);
    xdbl_reduce<<<(NROWS * 96) / 256, 256, 0, stream>>>(Pxdbl, xdtr, xbc);

    // 5. dt = softplus(xdtr @ Wdt + b) -> bf16  (MFMA, K=64)
    mfma_gemm<<<dim3(D_INNER / 128, NROWS / 128), 256, 0, stream>>>(
        xdtr, Wdtt, nullptr, D_INNER, DT_RANK, DT_RANK, 0, 4,
        bdt, D_INNER, dtbb);

    // 6-8. chunked selective scan (NC=64, r5-verified)
    scan_part1<<<dim3(D_INNER / 256, NC, BB), 256, 0, stream>>>(
        dtbb, xbc, xsb, A_log, Sbuf, Tbuf);
    scan_part2<<<(BB * D_INNER * D_STATE) / 256, 256, 0, stream>>>(
        Sbuf, Tbuf, A_log, Hin);
    scan_part3<<<dim3(D_INNER / 256, NC, BB), 256, 0, stream>>>(
        dtbb, xbc, xsb, xzb, A_log, Dp, Hin, ybuf, ssm_out);

    // 9. out_proj: pipelined 128x128, ring-4 (r5-verified) + fused residual
    mfma_out_pipe<<<dim3(D_MODEL / 128, NROWS / 128), 512, 0, stream>>>(
        ybuf, wtout, x, rscale, out);
}

// Round 12
// 275.427 us; speedup vs baseline: 1.0224x; 1.0224x over previous
//
#include <hip/hip_runtime.h>
#include <math.h>

#define D_MODEL 1024
#define D_STATE 16
#define D_CONVK 4
#define D_INNER 2048
#define DT_RANK 64
#define BB 2
#define LL 2048
#define NROWS (BB*LL)   // 4096
#define NC 64           // scan chunks
#define CH (LL/NC)      // 32 steps per chunk
#define XZLD 4096       // fused xz bf16 row stride
#define LOG2E 1.44269504088896340736f
#define LN2   0.69314718055994530942f

typedef __attribute__((ext_vector_type(8))) short bf16x8;
typedef __attribute__((ext_vector_type(8))) unsigned short u16x8;
typedef __attribute__((ext_vector_type(4))) float f32x4;

typedef __attribute__((address_space(3))) unsigned char lds_ucp;
typedef const __attribute__((address_space(1))) unsigned char glb_ucp;
#define GLD16(gp, lp) __builtin_amdgcn_global_load_lds((glb_ucp*)(gp), (lds_ucp*)(lp), 16, 0, 0)

__device__ inline unsigned short f2bf(float f) {
    union { float f; unsigned u; } c; c.f = f;
    unsigned r = c.u + 0x7fff + ((c.u >> 16) & 1);   // round-to-nearest-even
    return (unsigned short)(r >> 16);
}
__device__ inline float bf2f(unsigned short s) {
    union { unsigned u; float f; } c; c.u = ((unsigned)s) << 16;
    return c.f;
}
__device__ inline float fexp2(float x) { return __builtin_amdgcn_exp2f(x); }
__device__ inline float frcp(float x)  { return __builtin_amdgcn_rcpf(x); }
__device__ inline float fsilu(float x) { return x * frcp(1.0f + fexp2(-x * LOG2E)); }

// ---- merged prologue: LN (bx<4096) + all 4 weight transposes (bx>=4096) ----
__global__ __launch_bounds__(256)
void prologue_kernel(const float* __restrict__ x, const float* __restrict__ lw,
                     const float* __restrict__ lb, unsigned short* __restrict__ xnb,
                     const float* __restrict__ Win, const float* __restrict__ Wout,
                     const float* __restrict__ Wx, const float* __restrict__ Wdt,
                     unsigned short* __restrict__ wtin, unsigned short* __restrict__ wtout,
                     unsigned short* __restrict__ Wxt, unsigned short* __restrict__ Wdtt) {
    if (blockIdx.x < NROWS) {
        int row = blockIdx.x;
        const float* xr = x + (size_t)row * D_MODEL;
        float4 v = ((const float4*)xr)[threadIdx.x];
        float s  = v.x + v.y + v.z + v.w;
        float ss = v.x*v.x + v.y*v.y + v.z*v.z + v.w*v.w;
        for (int off = 32; off > 0; off >>= 1) {
            s  += __shfl_down(s, off);
            ss += __shfl_down(ss, off);
        }
        __shared__ float red[8];
        int lane = threadIdx.x & 63, wv = threadIdx.x >> 6;
        if (lane == 0) { red[wv] = s; red[wv + 4] = ss; }
        __syncthreads();
        if (threadIdx.x == 0) {
            float ts  = red[0] + red[1] + red[2] + red[3];
            float tss = red[4] + red[5] + red[6] + red[7];
            float mu  = ts / D_MODEL;
            float var = tss / D_MODEL - mu * mu;
            red[0] = mu; red[1] = rsqrtf(var + 1e-5f);
        }
        __syncthreads();
        float mu = red[0], rs = red[1];
        float4 w4 = ((const float4*)lw)[threadIdx.x];
        float4 b4 = ((const float4*)lb)[threadIdx.x];
        ushort4 o;
        o.x = f2bf((v.x - mu) * rs * w4.x + b4.x);
        o.y = f2bf((v.y - mu) * rs * w4.y + b4.y);
        o.z = f2bf((v.z - mu) * rs * w4.z + b4.z);
        o.w = f2bf((v.w - mu) * rs * w4.w + b4.w);
        ((ushort4*)(xnb + (size_t)row * D_MODEL))[threadIdx.x] = o;
        return;
    }
    int tb = blockIdx.x - NROWS;
    int bx = tb % 228, by = tb / 228;
    __shared__ float t[32][33];
    const float* W; unsigned short* Wt; int K, Nsrc, xb;
    if (bx < 128)      { W = Win;  Wt = wtin;  K = 1024; Nsrc = 4096; xb = bx; }
    else if (bx < 160) { W = Wout; Wt = wtout; K = 2048; Nsrc = 1024; xb = bx - 128; }
    else if (bx < 164) { W = Wx;   Wt = Wxt;   K = 2048; Nsrc = 96;   xb = bx - 160; }
    else               { W = Wdt;  Wt = Wdtt;  K = 64;   Nsrc = 2048; xb = bx - 164; }
    int k0 = by * 32, n0 = xb * 32;
    if (k0 >= K) return;
    int tx = threadIdx.x & 31, ty = threadIdx.x >> 5;
#pragma unroll
    for (int i = 0; i < 32; i += 8)
        t[ty + i][tx] = (n0 + tx < Nsrc)
            ? W[(size_t)(k0 + ty + i) * Nsrc + n0 + tx] : 0.0f;
    __syncthreads();
#pragma unroll
    for (int i = 0; i < 32; i += 8)
        Wt[(size_t)(n0 + ty + i) * K + k0 + tx] = f2bf(t[tx][ty + i]);
}

// ---- pipelined bf16 MFMA GEMM: 256x256, BK=32, 4-deep ring, 1 barrier/tile.
// SESSION-BEST VERIFIED STATE (r5: 41.5us in-kernel, 0 bank conflicts,
// VGPR=100, total 278.5us). Occupancy/tile/BK variations r6/r9/r11 all
// neutral-or-worse; in_proj is LDS-read-per-MFMA bound at this fragment
// reuse ratio (~6cyc LDS read per 4cyc MFMA) -- schedule is at its floor.
__global__ __launch_bounds__(512, 2)
void mfma_gemm_pipe(const unsigned short* __restrict__ A,
                    const unsigned short* __restrict__ Wt,
                    int ldc, int K, unsigned short* __restrict__ out2) {
    __shared__ short As[4][256 * 32];   // 64 KB
    __shared__ short Bs[4][256 * 32];   // 64 KB
    int tid = threadIdx.x;
    int lane = tid & 63, w = tid >> 6;
    int wm = w & 1, wn = w >> 1;
    // bijective XCD swizzle (grid size 256 % 8 == 0)
    int bid = blockIdx.y * gridDim.x + blockIdx.x;
    int cpx = (gridDim.x * gridDim.y) >> 3;
    int swz = (bid & 7) * cpx + (bid >> 3);
    int bx = swz % gridDim.x, by = swz / gridDim.x;
    int row0 = by * 256, col0 = bx * 256;
    const unsigned short* gA0 = A  + (size_t)row0 * K;
    const unsigned short* gB0 = Wt + (size_t)col0 * K;
    int rowin = lane >> 2;
    int scol  = ((lane & 3) ^ ((lane >> 3) & 3)) << 3;
    int quad = lane >> 4, r16 = lane & 15;
    int swr  = (r16 >> 1) & 3;              // read-side swizzle (row>>1)&3
    int cslot = ((quad ^ swr) << 3);
    f32x4 acc[8][4] = {};
    int nt = K >> 5;                        // 32 for K=1024

#define STAGE_A(tt) do { int _b = (tt) & 3; int _k0 = (tt) << 5;               \
    _Pragma("unroll")                                                          \
    for (int _l = 0; _l < 2; ++_l) {                                           \
        int _c = _l * 8 + w;                                                   \
        GLD16(gA0 + (size_t)(_c * 16 + rowin) * K + _k0 + scol,                \
              (char*)&As[_b][0] + _c * 1024);                                  \
    } } while (0)
#define STAGE_B(tt) do { int _b = (tt) & 3; int _k0 = (tt) << 5;               \
    _Pragma("unroll")                                                          \
    for (int _l = 0; _l < 2; ++_l) {                                           \
        int _c = _l * 8 + w;                                                   \
        GLD16(gB0 + (size_t)(_c * 16 + rowin) * K + _k0 + scol,                \
              (char*)&Bs[_b][0] + _c * 1024);                                  \
    } } while (0)

    STAGE_A(0); STAGE_B(0); STAGE_A(1); STAGE_B(1);   // 8 loads in flight

#pragma unroll 4
    for (int t = 0; t < nt; ++t) {
        // tile t resident when <=4 younger loads (stage t+1) remain in flight
        if (t < nt - 1) asm volatile("s_waitcnt vmcnt(4)" ::: "memory");
        else            asm volatile("s_waitcnt vmcnt(0)" ::: "memory");
        __builtin_amdgcn_s_barrier();
        const short* Ab = &As[t & 3][0];
        const short* Bb = &Bs[t & 3][0];
        bf16x8 bfr[4], af[8];
#pragma unroll
        for (int i = 0; i < 4; ++i)
            bfr[i] = *(const bf16x8*)&Bb[(wn * 64 + i * 16 + r16) * 32 + cslot];
#pragma unroll
        for (int i = 0; i < 8; ++i)
            af[i] = *(const bf16x8*)&Ab[(wm * 128 + i * 16 + r16) * 32 + cslot];
        if (t + 2 < nt) { STAGE_A(t + 2); STAGE_B(t + 2); }
        __builtin_amdgcn_s_setprio(1);
#pragma unroll
        for (int mi = 0; mi < 8; ++mi)
#pragma unroll
            for (int ni = 0; ni < 4; ++ni)
                acc[mi][ni] = __builtin_amdgcn_mfma_f32_16x16x32_bf16(
                    af[mi], bfr[ni], acc[mi][ni], 0, 0, 0);
        __builtin_amdgcn_s_setprio(0);
    }
#undef STAGE_A
#undef STAGE_B
    int odd = lane & 1;
#pragma unroll
    for (int mi = 0; mi < 8; ++mi)
#pragma unroll
        for (int ni = 0; ni < 4; ++ni) {
            int colE = col0 + wn * 64 + ni * 16 + r16;
#pragma unroll
            for (int rp = 0; rp < 2; ++rp) {
                int rowE = row0 + wm * 128 + mi * 16 + quad * 4 + rp * 2;
                int row  = rowE + odd;
                int colp = colE - odd;
                unsigned hh = (unsigned)f2bf(acc[mi][ni][rp*2]) |
                              ((unsigned)f2bf(acc[mi][ni][rp*2+1]) << 16);
                unsigned ph = __shfl_xor((int)hh, 1);
                unsigned u_even = (hh & 0xffffu) | (ph << 16);
                unsigned u_odd  = (ph >> 16) | (hh & 0xffff0000u);
                unsigned u = odd ? u_odd : u_even;
                *(unsigned*)&out2[(size_t)row * ldc + colp] = u;
            }
        }
}

// ---- pipelined out_proj: 128x128, BK=64, 4-deep ring, 1 barrier/tile,
// fused epilogue out = rs*acc + residual. SESSION-BEST VERIFIED (r5).
__global__ __launch_bounds__(512, 2)
void mfma_out_pipe(const unsigned short* __restrict__ A,
                   const unsigned short* __restrict__ Wt,
                   const float* __restrict__ x, const float* __restrict__ rscale,
                   float* __restrict__ out) {
    __shared__ short As[4][128 * 64];   // 64 KB
    __shared__ short Bs[4][128 * 64];   // 64 KB
    const int K = D_INNER;              // 2048
    int tid = threadIdx.x;
    int lane = tid & 63, w = tid >> 6;
    int wm = w & 1, wn = w >> 1;        // 2 M-strips(64) x 4 N-strips(32)
    // bijective XCD swizzle (grid 256 % 8 == 0)
    int bid = blockIdx.y * gridDim.x + blockIdx.x;
    int cpx = (gridDim.x * gridDim.y) >> 3;
    int swz = (bid & 7) * cpx + (bid >> 3);
    int bx = swz % gridDim.x, by = swz / gridDim.x;
    int row0 = by * 128, col0 = bx * 128;
    const unsigned short* gA0 = A  + (size_t)row0 * K;
    const unsigned short* gB0 = Wt + (size_t)col0 * K;
    int row8 = lane >> 3;
    int scol = ((lane & 7) ^ row8) << 3;
    int quad = lane >> 4, r16 = lane & 15;
    int sw7  = r16 & 7;                 // read-side swizzle row&7
    f32x4 acc[4][2] = {};
    const int nt = K >> 6;              // 32

#define OSTG(gp, buf, tt) do { int _b = (tt) & 3; int _k0 = (tt) << 6;         \
    _Pragma("unroll")                                                          \
    for (int _l = 0; _l < 2; ++_l) {                                           \
        int _c = _l * 8 + w;                                                   \
        GLD16(gp + (size_t)(_c * 8 + row8) * K + _k0 + scol,                   \
              (char*)&buf[_b][0] + _c * 1024);                                 \
    } } while (0)

    OSTG(gA0, As, 0); OSTG(gB0, Bs, 0); OSTG(gA0, As, 1); OSTG(gB0, Bs, 1);

#pragma unroll 4
    for (int t = 0; t < nt; ++t) {
        if (t < nt - 1) asm volatile("s_waitcnt vmcnt(4)" ::: "memory");
        else            asm volatile("s_waitcnt vmcnt(0)" ::: "memory");
        __builtin_amdgcn_s_barrier();
        const short* Ab = &As[t & 3][0];
        const short* Bb = &Bs[t & 3][0];
        int cs0 = ((quad ^ sw7) << 3);
        int cs1 = (((4 + quad) ^ sw7) << 3);
        bf16x8 af0[4], af1[4], bf0[2], bf1[2];
#pragma unroll
        for (int i = 0; i < 2; ++i) {
            bf0[i] = *(const bf16x8*)&Bb[(wn * 32 + i * 16 + r16) * 64 + cs0];
            bf1[i] = *(const bf16x8*)&Bb[(wn * 32 + i * 16 + r16) * 64 + cs1];
        }
#pragma unroll
        for (int i = 0; i < 4; ++i) {
            af0[i] = *(const bf16x8*)&Ab[(wm * 64 + i * 16 + r16) * 64 + cs0];
            af1[i] = *(const bf16x8*)&Ab[(wm * 64 + i * 16 + r16) * 64 + cs1];
        }
        if (t + 2 < nt) { OSTG(gA0, As, t + 2); OSTG(gB0, Bs, t + 2); }
        __builtin_amdgcn_s_setprio(1);
#pragma unroll
        for (int mi = 0; mi < 4; ++mi)
#pragma unroll
            for (int ni = 0; ni < 2; ++ni)
                acc[mi][ni] = __builtin_amdgcn_mfma_f32_16x16x32_bf16(
                    af0[mi], bf0[ni], acc[mi][ni], 0, 0, 0);
#pragma unroll
        for (int mi = 0; mi < 4; ++mi)
#pragma unroll
            for (int ni = 0; ni < 2; ++ni)
                acc[mi][ni] = __builtin_amdgcn_mfma_f32_16x16x32_bf16(
                    af1[mi], bf1[ni], acc[mi][ni], 0, 0, 0);
        __builtin_amdgcn_s_setprio(0);
    }
#undef OSTG
    // fused epilogue: out = rs*acc + residual (pair-packed fp32, proven)
    float rs = rscale[0];
    int odd = lane & 1;
#pragma unroll
    for (int mi = 0; mi < 4; ++mi)
#pragma unroll
        for (int ni = 0; ni < 2; ++ni) {
            int colE = col0 + wn * 32 + ni * 16 + r16;
#pragma unroll
            for (int rp = 0; rp < 2; ++rp) {
                int rowE = row0 + wm * 64 + mi * 16 + quad * 4 + rp * 2;
                int row  = rowE + odd;
                int colp = colE - odd;
                float a0 = acc[mi][ni][rp*2], a1 = acc[mi][ni][rp*2+1];
                float b0 = __shfl_xor(a0, 1), b1 = __shfl_xor(a1, 1);
                float2 f2;
                f2.x = odd ? b1 : a0;
                f2.y = odd ? a1 : b0;
                float2 xr = *(const float2*)&x[(size_t)row * D_MODEL + colp];
                float2 o2;
                o2.x = rs * f2.x + xr.x;
                o2.y = rs * f2.y + xr.y;
                *(float2*)&out[(size_t)row * D_MODEL + colp] = o2;
            }
        }
}

// ---------------- bf16 MFMA GEMM: 128x128, 256 threads, BK=64 --------------
// mode 0: fp32 pair-packed if col<Ncols | mode 4: softplus(acc+aux[col]) bf16
__global__ __launch_bounds__(256)
void mfma_gemm(const unsigned short* __restrict__ A,
               const unsigned short* __restrict__ Wt,
               float* __restrict__ C, int ldc, int K, int kchunk,
               size_t zstride, int mode,
               const float* __restrict__ aux,
               int Ncols, unsigned short* __restrict__ out2) {
    __shared__ short As[128 * 64];
    __shared__ short Bs[128 * 64];
    int tid = threadIdx.x;
    int lane = tid & 63, w = tid >> 6;
    int wm = w & 1, wn = w >> 1;
    int row0 = blockIdx.y * 128, col0 = blockIdx.x * 128;
    int kb = blockIdx.z * kchunk, ke = kb + kchunk;
    C += (size_t)blockIdx.z * zstride;
    f32x4 acc[4][4] = {};
    const unsigned short* gA0 = A  + (size_t)row0 * K;
    const unsigned short* gB0 = Wt + (size_t)col0 * K;
    int r_in = lane >> 3;
    int e16  = (lane & 7) * 8;
    int quad = lane >> 4, r16 = lane & 15;
    for (int k0 = kb; k0 < ke; k0 += 64) {
        __syncthreads();
#pragma unroll
        for (int t = 0; t < 4; ++t) {
            int p = w * 4 + t;
            int row = p * 8 + r_in;
            GLD16(gA0 + (size_t)row * K + k0 + e16, (char*)As + p * 1024);
            GLD16(gB0 + (size_t)row * K + k0 + e16, (char*)Bs + p * 1024);
        }
        __syncthreads();
#pragma unroll
        for (int ks = 0; ks < 2; ++ks) {
            bf16x8 af[4], bfr[4];
#pragma unroll
            for (int i = 0; i < 4; ++i) {
                af[i]  = *(const bf16x8*)&As[(wm * 64 + i * 16 + r16) * 64 + ks * 32 + quad * 8];
                bfr[i] = *(const bf16x8*)&Bs[(wn * 64 + i * 16 + r16) * 64 + ks * 32 + quad * 8];
            }
#pragma unroll
            for (int mi = 0; mi < 4; ++mi)
#pragma unroll
                for (int ni = 0; ni < 4; ++ni)
                    acc[mi][ni] = __builtin_amdgcn_mfma_f32_16x16x32_bf16(
                        af[mi], bfr[ni], acc[mi][ni], 0, 0, 0);
        }
    }
    int odd = lane & 1;
#pragma unroll
    for (int mi = 0; mi < 4; ++mi)
#pragma unroll
        for (int ni = 0; ni < 4; ++ni) {
            int colE = col0 + wn * 64 + ni * 16 + r16;
            float v[4];
#pragma unroll
            for (int r = 0; r < 4; ++r) v[r] = acc[mi][ni][r];
            if (mode == 4) {
                float bv = aux[colE];
#pragma unroll
                for (int r = 0; r < 4; ++r) {
                    float tv = v[r] + bv;
                    v[r] = (tv > 20.0f) ? tv
                         : LN2 * __builtin_amdgcn_logf(1.0f + fexp2(tv * LOG2E));
                }
            }
#pragma unroll
            for (int rp = 0; rp < 2; ++rp) {
                int rowE = row0 + wm * 64 + mi * 16 + quad * 4 + rp * 2;
                int row  = rowE + odd;
                int colp = colE - odd;
                if (mode >= 3) {
                    unsigned hh = (unsigned)f2bf(v[rp*2]) | ((unsigned)f2bf(v[rp*2+1]) << 16);
                    unsigned ph = __shfl_xor((int)hh, 1);
                    unsigned u_even = (hh & 0xffffu) | (ph << 16);
                    unsigned u_odd  = (ph >> 16) | (hh & 0xffff0000u);
                    unsigned u = odd ? u_odd : u_even;
                    *(unsigned*)&out2[(size_t)row * ldc + colp] = u;
                } else {
                    float a0 = v[rp*2], a1 = v[rp*2+1];
                    float b0 = __shfl_xor(a0, 1), b1 = __shfl_xor(a1, 1);
                    float2 f2;
                    f2.x = odd ? b1 : a0;
                    f2.y = odd ? a1 : b0;
                    if (colp < Ncols)
                        *(float2*)&C[(size_t)row * ldc + colp] = f2;
                }
            }
        }
}

// ---- reduce 8 split-K partials of x_dbl; emit dt-rank bf16 + B|C fp32 ----
__global__ __launch_bounds__(256)
void xdbl_reduce(const float* __restrict__ P,
                 unsigned short* __restrict__ xdtr, float* __restrict__ xbc) {
    const int S1 = NROWS * 96;
    int t = blockIdx.x * 256 + threadIdx.x;
    float s = 0.0f;
#pragma unroll
    for (int k = 0; k < 8; ++k) s += P[t + k * S1];
    int row = t / 96, col = t - row * 96;
    if (col < DT_RANK) xdtr[(size_t)row * DT_RANK + col] = f2bf(s);
    else xbc[(size_t)row * 32 + col - DT_RANK] = s;
}

// ---- Causal depthwise conv (K=4) + bias + silu, bf16 in/out, vectorized ----
__global__ __launch_bounds__(256)
void conv_kernel(const unsigned short* __restrict__ xzb, const float* __restrict__ cw,
                 const float* __restrict__ cb, unsigned short* __restrict__ xs,
                 float* __restrict__ conv_state_out) {
    int loct = blockIdx.x & 255;
    int b    = blockIdx.x >> 8;
    int d0   = threadIdx.x * 8;
    float wgt[8][4];
#pragma unroll
    for (int j = 0; j < 8; ++j) {
        float4 w4 = *(const float4*)(cw + (size_t)(d0 + j) * 4);
        wgt[j][0] = w4.x; wgt[j][1] = w4.y; wgt[j][2] = w4.z; wgt[j][3] = w4.w;
    }
    float bias[8];
    *(float4*)&bias[0] = *(const float4*)(cb + d0);
    *(float4*)&bias[4] = *(const float4*)(cb + d0 + 4);
    float xr[11][8];
#pragma unroll
    for (int r = 0; r < 11; ++r) {
        int l = loct * 8 - 3 + r;
        if (l >= 0) {
            u16x8 v = *(const u16x8*)&xzb[((size_t)b * LL + l) * XZLD + d0];
#pragma unroll
            for (int j = 0; j < 8; ++j) xr[r][j] = bf2f(v[j]);
        } else {
#pragma unroll
            for (int j = 0; j < 8; ++j) xr[r][j] = 0.0f;
        }
    }
#pragma unroll
    for (int i = 0; i < 8; ++i) {
        unsigned short o[8];
#pragma unroll
        for (int j = 0; j < 8; ++j) {
            float a = bias[j];
#pragma unroll
            for (int k = 0; k < 4; ++k) a = fmaf(xr[i + k][j], wgt[j][k], a);
            o[j] = f2bf(fsilu(a));
        }
        *(u16x8*)&xs[((size_t)b * LL + loct * 8 + i) * D_INNER + d0] = *(u16x8*)o;
    }
    if (loct == 255) {
#pragma unroll
        for (int i = 8; i < 11; ++i)
#pragma unroll
            for (int j = 0; j < 8; ++j)
                conv_state_out[((size_t)b * D_INNER + d0 + j) * 3 + (i - 8)] = xr[i][j];
    }
}

// ---------------- Selective scan: thread-per-d, 16 n-states in regs --------
// Pass 1: chunk-local scan S[16] + Tsum (chunk dt sum). E never materialized.
__global__ __launch_bounds__(256)
void scan_part1(const unsigned short* __restrict__ dt, const float* __restrict__ xbc,
                const unsigned short* __restrict__ xs,
                const float* __restrict__ A_log,
                float* __restrict__ Sbuf, float* __restrict__ Tbuf) {
    __shared__ float Bs[CH][32];
    int d = blockIdx.x * 256 + threadIdx.x;
    int c = blockIdx.y, b = blockIdx.z;
    size_t rowbase = (size_t)b * LL + (size_t)c * CH;
    for (int e = threadIdx.x; e < CH * 32; e += 256) {
        int i = e >> 5, j = e & 31;
        Bs[i][j] = xbc[(rowbase + i) * 32 + j];
    }
    float al2[16];
    {
        const float4* ap = (const float4*)(A_log + (size_t)d * D_STATE);
#pragma unroll
        for (int q = 0; q < 4; ++q) {
            float4 a4 = ap[q];
            al2[q*4+0] = -fexp2(a4.x * LOG2E) * LOG2E;
            al2[q*4+1] = -fexp2(a4.y * LOG2E) * LOG2E;
            al2[q*4+2] = -fexp2(a4.z * LOG2E) * LOG2E;
            al2[q*4+3] = -fexp2(a4.w * LOG2E) * LOG2E;
        }
    }
    __syncthreads();
    float S[16];
#pragma unroll
    for (int n = 0; n < 16; ++n) S[n] = 0.0f;
    float Tsum = 0.0f;
    float dtv = bf2f(dt[rowbase * D_INNER + d]);
    float xv  = bf2f(xs[rowbase * D_INNER + d]);
    for (int i = 0; i < CH; ++i) {
        float dtn = 0.0f, xn2 = 0.0f;
        if (i + 1 < CH) {
            size_t r2 = (rowbase + i + 1) * D_INNER + d;
            dtn = bf2f(dt[r2]); xn2 = bf2f(xs[r2]);
        }
        Tsum += dtv;
        float dtx = dtv * xv;
#pragma unroll
        for (int q = 0; q < 4; ++q) {
            float4 Bv = *(const float4*)&Bs[i][q * 4];
            S[q*4+0] = fmaf(fexp2(al2[q*4+0] * dtv), S[q*4+0], dtx * Bv.x);
            S[q*4+1] = fmaf(fexp2(al2[q*4+1] * dtv), S[q*4+1], dtx * Bv.y);
            S[q*4+2] = fmaf(fexp2(al2[q*4+2] * dtv), S[q*4+2], dtx * Bv.z);
            S[q*4+3] = fmaf(fexp2(al2[q*4+3] * dtv), S[q*4+3], dtx * Bv.w);
        }
        dtv = dtn; xv = xn2;
    }
    size_t o = (((size_t)b * NC + c) * D_INNER + d) * D_STATE;
#pragma unroll
    for (int q = 0; q < 4; ++q) {
        float4 Sv;
        Sv.x = S[q*4+0]; Sv.y = S[q*4+1]; Sv.z = S[q*4+2]; Sv.w = S[q*4+3];
        *(float4*)(Sbuf + o + q * 4) = Sv;
    }
    Tbuf[((size_t)b * NC + c) * D_INNER + d] = Tsum;
}

// Pass 2: fold chunks; E recomputed from Tsum. Hin aliases Sbuf (load-then-store).
__global__ __launch_bounds__(256)
void scan_part2(const float* __restrict__ S, const float* __restrict__ Tbuf,
                const float* __restrict__ A_log, float* __restrict__ Hin) {
    int t = blockIdx.x * 256 + threadIdx.x;
    int b = t >> 15;
    int rem = t & 32767;          // d*16+n
    int d = rem >> 4;
    float al2 = -fexp2(A_log[rem] * LOG2E) * LOG2E;
    size_t sbase = (size_t)b * NC * (D_INNER * D_STATE) + rem;
    size_t tbase = (size_t)b * NC * D_INNER + d;
    float h = 0.0f;
    for (int c = 0; c < NC; ++c) {
        size_t sq = sbase + (size_t)c * (D_INNER * D_STATE);
        float s = S[sq];
        float T = Tbuf[tbase + (size_t)c * D_INNER];
        Hin[sq] = h;
        h = fmaf(fexp2(al2 * T), h, s);
    }
}

// Pass 3: local scan with h_in; emits y (bf16) and final ssm state.
__global__ __launch_bounds__(256)
void scan_part3(const unsigned short* __restrict__ dt, const float* __restrict__ xbc,
                const unsigned short* __restrict__ xs,
                const unsigned short* __restrict__ xzb,  // z at col 2048+, stride XZLD
                const float* __restrict__ A_log, const float* __restrict__ Dp,
                const float* __restrict__ Hin,
                unsigned short* __restrict__ y, float* __restrict__ ssm_out) {
    __shared__ float Bs[CH][32];
    int d = blockIdx.x * 256 + threadIdx.x;
    int c = blockIdx.y, b = blockIdx.z;
    size_t rowbase = (size_t)b * LL + (size_t)c * CH;
    for (int e = threadIdx.x; e < CH * 32; e += 256) {
        int i = e >> 5, j = e & 31;
        Bs[i][j] = xbc[(rowbase + i) * 32 + j];
    }
    float al2[16];
    {
        const float4* ap = (const float4*)(A_log + (size_t)d * D_STATE);
#pragma unroll
        for (int q = 0; q < 4; ++q) {
            float4 a4 = ap[q];
            al2[q*4+0] = -fexp2(a4.x * LOG2E) * LOG2E;
            al2[q*4+1] = -fexp2(a4.y * LOG2E) * LOG2E;
            al2[q*4+2] = -fexp2(a4.z * LOG2E) * LOG2E;
            al2[q*4+3] = -fexp2(a4.w * LOG2E) * LOG2E;
        }
    }
    float Dv = Dp[d];
    float h[16];
    {
        const float4* hp = (const float4*)(Hin + (((size_t)b * NC + c) * D_INNER + d) * D_STATE);
#pragma unroll
        for (int q = 0; q < 4; ++q) {
            float4 h4 = hp[q];
            h[q*4+0] = h4.x; h[q*4+1] = h4.y; h[q*4+2] = h4.z; h[q*4+3] = h4.w;
        }
    }
    __syncthreads();
    size_t r0 = rowbase * D_INNER + d;
    float dtv = bf2f(dt[r0]);
    float xv  = bf2f(xs[r0]);
    float zv  = bf2f(xzb[rowbase * XZLD + D_INNER + d]);
    for (int i = 0; i < CH; ++i) {
        float dtn = 0.0f, xn2 = 0.0f, zn2 = 0.0f;
        if (i + 1 < CH) {
            size_t r2 = (rowbase + i + 1) * D_INNER + d;
            dtn = bf2f(dt[r2]); xn2 = bf2f(xs[r2]);
            zn2 = bf2f(xzb[(rowbase + i + 1) * XZLD + D_INNER + d]);
        }
        float dtx = dtv * xv;
        float yv = 0.0f;
#pragma unroll
        for (int q = 0; q < 4; ++q) {
            float4 Bv = *(const float4*)&Bs[i][q * 4];
            float4 Cv = *(const float4*)&Bs[i][16 + q * 4];
            h[q*4+0] = fmaf(fexp2(al2[q*4+0] * dtv), h[q*4+0], dtx * Bv.x);
            h[q*4+1] = fmaf(fexp2(al2[q*4+1] * dtv), h[q*4+1], dtx * Bv.y);
            h[q*4+2] = fmaf(fexp2(al2[q*4+2] * dtv), h[q*4+2], dtx * Bv.z);
            h[q*4+3] = fmaf(fexp2(al2[q*4+3] * dtv), h[q*4+3], dtx * Bv.w);
            yv = fmaf(h[q*4+0], Cv.x, yv);
            yv = fmaf(h[q*4+1], Cv.y, yv);
            yv = fmaf(h[q*4+2], Cv.z, yv);
            yv = fmaf(h[q*4+3], Cv.w, yv);
        }
        yv = (yv + xv * Dv) * fsilu(zv);
        y[(rowbase + i) * D_INNER + d] = f2bf(yv);
        dtv = dtn; xv = xn2; zv = zn2;
    }
    if (c == NC - 1) {
        float* sp = ssm_out + ((size_t)b * D_INNER + d) * D_STATE;
#pragma unroll
        for (int q = 0; q < 4; ++q) {
            float4 h4;
            h4.x = h[q*4+0]; h4.y = h[q*4+1]; h4.z = h[q*4+2]; h4.w = h[q*4+3];
            *(float4*)(sp + q * 4) = h4;
        }
    }
}

// ---------------- launch ----------------
extern "C" void kernel_launch(void* const* d_in, const int* in_sizes, int n_in,
                              void* d_out, int out_size, void* d_ws, size_t ws_size,
                              hipStream_t stream) {
    (void)in_sizes; (void)n_in; (void)out_size; (void)ws_size;
    const float* x      = (const float*)d_in[0];
    const float* ln_w   = (const float*)d_in[1];
    const float* ln_b   = (const float*)d_in[2];
    const float* Win    = (const float*)d_in[3];   // [1024, 4096]
    const float* convw  = (const float*)d_in[4];   // [2048, 4]
    const float* convb  = (const float*)d_in[5];
    const float* Wx     = (const float*)d_in[6];   // [2048, 96]
    const float* Wdt    = (const float*)d_in[7];   // [64, 2048]
    const float* bdt    = (const float*)d_in[8];
    const float* A_log  = (const float*)d_in[9];   // [2048, 16]
    const float* Dp     = (const float*)d_in[10];
    const float* Wout   = (const float*)d_in[11];  // [2048, 1024]
    const float* rscale = (const float*)d_in[12];  // [1]

    float* out      = (float*)d_out;
    float* ssm_out  = out + (size_t)NROWS * D_MODEL;
    float* conv_out = ssm_out + (size_t)BB * D_INNER * D_STATE;

    // ---- workspace layout ----
    float* ws = (float*)d_ws;
    unsigned short* xzb = (unsigned short*)ws;                     // 33.55 MB bf16
    unsigned short* xsb = xzb + (size_t)NROWS * XZLD;              // 16.78 MB bf16
    unsigned short* dtbb = xsb + (size_t)NROWS * D_INNER;          // 16.78 MB bf16
    float* xbc  = (float*)(dtbb + (size_t)NROWS * D_INNER);        // 0.52 MB
    unsigned short* xdtr = (unsigned short*)(xbc + (size_t)NROWS * 32);  // 0.52 MB
    unsigned short* xnb  = xdtr + (size_t)NROWS * DT_RANK;         // 8.39 MB
    unsigned short* wtin = xnb + (size_t)NROWS * D_MODEL;          // 8.39 MB
    unsigned short* wtout = wtin + (size_t)(2 * D_INNER) * D_MODEL; // 4.19 MB
    unsigned short* Wxt  = wtout + (size_t)D_MODEL * D_INNER;      // 0.52 MB
    unsigned short* Wdtt = Wxt + (size_t)128 * D_INNER;            // 0.26 MB
    float* Tbuf = (float*)(Wdtt + (size_t)D_INNER * DT_RANK);      // 1.05 MB (NC=64)
    float* Sbuf = Tbuf + (size_t)BB * NC * D_INNER;                // 16.78 MB (NC=64)
    // aliases (disjoint lifetimes within Sbuf region):
    float* Pxdbl = Sbuf;                         // 12.58 MB, dead before scan1
    float* Hin   = Sbuf;                         // pass2 out (load-before-store)
    unsigned short* ybuf = xnb;                  // y bf16 spans xnb+wtin (dead)

    // 1. LN + all weight transposes (one launch)
    prologue_kernel<<<NROWS + 228 * 64, 256, 0, stream>>>(
        x, ln_w, ln_b, xnb, Win, Wout, Wx, Wdt, wtin, wtout, Wxt, Wdtt);

    // 2. in_proj: pipelined 256x256, BK=32, ring-4 (r5-verified 41.5us)
    mfma_gemm_pipe<<<dim3(2 * D_INNER / 256, NROWS / 256), 512, 0, stream>>>(
        xnb, wtin, XZLD, D_MODEL, xzb);

    // 3. conv + silu -> bf16 x_s (+ conv_state)
    conv_kernel<<<BB * (LL / 8), 256, 0, stream>>>(
        xzb, convw, convb, xsb, conv_out);

    // 4. x_dbl split-K x8 -> partials (MFMA), then reduce
    mfma_gemm<<<dim3(1, NROWS / 128, 8), 256, 0, stream>>>(
        xsb, Wxt, Pxdbl, 96, D_INNER, D_INNER / 8, (size_t)NROWS * 96, 0,
        nullptr, 96, nullptr);
    xdbl_reduce<<<(NROWS * 96) / 256, 256, 0, stream>>>(Pxdbl, xdtr, xbc);

    // 5. dt = softplus(xdtr @ Wdt + b) -> bf16  (MFMA, K=64)
    mfma_gemm<<<dim3(D_INNER / 128, NROWS / 128), 256, 0, stream>>>(
        xdtr, Wdtt, nullptr, D_INNER, DT_RANK, DT_RANK, 0, 4,
        bdt, D_INNER, dtbb);

    // 6-8. chunked selective scan (NC=64, r5-verified)
    scan_part1<<<dim3(D_INNER / 256, NC, BB), 256, 0, stream>>>(
        dtbb, xbc, xsb, A_log, Sbuf, Tbuf);
    scan_part2<<<(BB * D_INNER * D_STATE) / 256, 256, 0, stream>>>(
        Sbuf, Tbuf, A_log, Hin);
    scan_part3<<<dim3(D_INNER / 256, NC, BB), 256, 0, stream>>>(
        dtbb, xbc, xsb, xzb, A_log, Dp, Hin, ybuf, ssm_out);

    // 9. out_proj: pipelined 128x128, ring-4 (r5-verified) + fused residual
    mfma_out_pipe<<<dim3(D_MODEL / 128, NROWS / 128), 512, 0, stream>>>(
        ybuf, wtout, x, rscale, out);
}